// Round 7
// baseline (276.313 us; speedup 1.0000x reference)
//
#include <hip/hip_runtime.h>
#include <hip/hip_bf16.h>
#include <math.h>

#define GG 8192      // graphs = B*T
#define NODESN 23
#define KK 8
#define DIN 16
#define HH 128
#define RHH 128
#define EPG (NODESN*KK)   // 184 edges per graph
#define TTT 128
#define BBB 64

// ---------------------------------------------------------------------------
// Kernel 1: per-graph GCN up to hsum (layer-1 + neighborhood aggregation).
// ---------------------------------------------------------------------------
__global__ __launch_bounds__(256) void gcn_hsum(
    const float* __restrict__ x, const int* __restrict__ esrc,
    const int* __restrict__ runner,
    const float* __restrict__ W1, const float* __restrict__ b1,
    float* __restrict__ hsum_g)
{
    __shared__ float xs[NODESN * DIN];
    __shared__ int   srcs[EPG];
    __shared__ float t1[NODESN * HH];
    __shared__ float red[256];

    const int g   = blockIdx.x;
    const int tid = threadIdx.x;
    const int j   = tid & 127;
    const int nh  = tid >> 7;

    for (int i = tid; i < NODESN * DIN; i += 256) xs[i] = x[g * NODESN * DIN + i];
    for (int i = tid; i < EPG; i += 256)          srcs[i] = esrc[g * EPG + i] - g * NODESN;

    float w[DIN];
    #pragma unroll
    for (int k = 0; k < DIN; k++) w[k] = W1[k * HH + j];
    const float b1j = b1[j];
    __syncthreads();

    const int n0 = nh * 12;
    const int n1 = nh ? NODESN : 12;
    for (int n = n0; n < n1; n++) {
        float acc = 0.f;
        #pragma unroll
        for (int k = 0; k < DIN; k += 4) {
            float4 xv = *(const float4*)&xs[n * DIN + k];
            acc = fmaf(xv.x, w[k], fmaf(xv.y, w[k+1], fmaf(xv.z, w[k+2], fmaf(xv.w, w[k+3], acc))));
        }
        t1[n * HH + j] = acc;
    }
    __syncthreads();

    const int r = runner[g];
    float part = 0.f;
    for (int slot = nh; slot < 9; slot += 2) {
        int node = (slot < 8) ? srcs[r * KK + slot] : r;
        float acc = t1[node * HH + j];
        #pragma unroll
        for (int k = 0; k < KK; k++) acc += t1[srcs[node * KK + k] * HH + j];
        part += fmaxf(acc * (1.f / 9.f) + b1j, 0.f);
    }
    red[tid] = part;
    __syncthreads();
    if (tid < HH) hsum_g[(size_t)g * HH + tid] = red[tid] + red[tid + 128];
}

// ---------------------------------------------------------------------------
// Kernel 2: seq = relu((1/9) * hsum @ W2 + b2), 16 graphs per block.
// ---------------------------------------------------------------------------
__global__ __launch_bounds__(256) void seq_kernel(
    const float* __restrict__ hsum_g, const float* __restrict__ W2,
    const float* __restrict__ b2, float* __restrict__ seq)
{
    __shared__ float hs[16 * HH];
    const int tid = threadIdx.x;
    const int j = tid & 127, mh = tid >> 7;
    const size_t base = (size_t)blockIdx.x * 16 * HH;

    for (int v = tid; v < 16 * HH / 4; v += 256)
        ((float4*)hs)[v] = ((const float4*)(hsum_g + base))[v];
    __syncthreads();

    float acc[8];
    #pragma unroll
    for (int m = 0; m < 8; m++) acc[m] = 0.f;
    const float* hrow = hs + mh * 8 * HH;
    for (int k = 0; k < HH; k += 4) {
        float w0  = W2[(k+0)*HH + j];
        float w1  = W2[(k+1)*HH + j];
        float w2v = W2[(k+2)*HH + j];
        float w3  = W2[(k+3)*HH + j];
        #pragma unroll
        for (int m = 0; m < 8; m++) {
            float4 hv = *(const float4*)&hrow[m * HH + k];
            acc[m] = fmaf(hv.x, w0, fmaf(hv.y, w1, fmaf(hv.z, w2v, fmaf(hv.w, w3, acc[m]))));
        }
    }
    const float bj = b2[j];
    #pragma unroll
    for (int m = 0; m < 8; m++)
        seq[base + (size_t)(mh * 8 + m) * HH + j] = fmaxf(acc[m] * (1.f/9.f) + bj, 0.f);
}

// ---------------------------------------------------------------------------
// Kernel 3: transpose W_ih [384,128] -> WT [128,384]
// ---------------------------------------------------------------------------
__global__ void transpose_wih(const float* __restrict__ W, float* __restrict__ WT)
{
    int idx = blockIdx.x * 256 + threadIdx.x;
    if (idx < 3 * RHH * RHH) {
        int jj = idx / RHH, kk = idx - jj * RHH;
        WT[kk * (3 * RHH) + jj] = W[idx];
    }
}

// ---------------------------------------------------------------------------
// Kernel 4: xg = seq @ W_ih^T + b_ih   [8192,128]@[128,384]
// ---------------------------------------------------------------------------
__global__ __launch_bounds__(384) void xg_kernel(
    const float* __restrict__ seq, const float* __restrict__ WT,
    const float* __restrict__ b_ih, float* __restrict__ xg)
{
    const int tid = threadIdx.x;
    const int m0 = blockIdx.x * 8;
    const float* srow = seq + (size_t)m0 * RHH;
    float acc[8];
    const float bv = b_ih[tid];
    #pragma unroll
    for (int mi = 0; mi < 8; mi++) acc[mi] = bv;
    for (int k = 0; k < RHH; k += 4) {
        float w0 = WT[(k+0)*384 + tid];
        float w1 = WT[(k+1)*384 + tid];
        float w2 = WT[(k+2)*384 + tid];
        float w3 = WT[(k+3)*384 + tid];
        #pragma unroll
        for (int mi = 0; mi < 8; mi++) {
            float4 sv = *(const float4*)(srow + mi * RHH + k);
            acc[mi] = fmaf(sv.x, w0, fmaf(sv.y, w1, fmaf(sv.z, w2, fmaf(sv.w, w3, acc[mi]))));
        }
    }
    #pragma unroll
    for (int mi = 0; mi < 8; mi++)
        xg[(size_t)(m0 + mi) * 384 + tid] = acc[mi];
}

// ---------------------------------------------------------------------------
// Kernel 5: GRU. 1024 threads per batch element.
// Thread (i,q): i = hidden unit (0..127), q = k-eighth (0..7) -> only 48
// W_hh floats/thread (~80 live VGPRs total, under even R6's 88-reg grant).
// q sits in lane bits [3:5] so the 8 partials reduce via __shfl_xor(8/16/32);
// afterwards ALL q-lanes redundantly compute the gate math (no masked tail).
// 82944 B static LDS keeps the 1-block/CU lock (16 waves = 4 waves/EU ->
// 128-VGPR budget). Plain __syncthreads(): the old asm barrier's "memory"
// clobber legally invalidated register-cached W_hh loads -> remat every step.
// ---------------------------------------------------------------------------
#define SMEM_FLOATS 20736   // 82944 bytes: 2 blocks would need > 160 KiB
#define XG0 0               // xg double buffer: [0,384) and [384,768)
#define HB0 768             // h ping-pong: [768,896) and [896,1024)

__global__ __launch_bounds__(1024)
__attribute__((amdgpu_waves_per_eu(4, 4)))
void gru_kernel(
    const float* __restrict__ xg, const float* __restrict__ W_hh,
    const float* __restrict__ b_hh, float* __restrict__ h_out)
{
    __shared__ float smem[SMEM_FLOATS];

    const int b    = blockIdx.x;
    const int tid  = threadIdx.x;
    const int lane = tid & 63;
    const int q    = lane >> 3;                          // k-eighth 0..7
    const int i    = ((tid >> 6) << 3) | (lane & 7);     // hidden unit 0..127

    if (tid == 0) smem[SMEM_FLOATS - 1] = 0.f;

    // ---- preload W_hh slices (rows i, 128+i, 256+i; cols [16q,16q+16)),
    // phase-rotated (p = (m+q)&3) to spread bank groups across q.
    float wr[16], wz[16], wn[16];
    int loff[4];
    {
        const float* br = W_hh + (size_t)i * RHH;
        const float* bz = br + (size_t)RHH * RHH;
        const float* bn = bz + (size_t)RHH * RHH;
        #pragma unroll
        for (int m = 0; m < 4; m++) {
            int p = (m + q) & 3;
            int o = q * 16 + 4 * p;
            loff[m] = o;
            float4 v;
            v = *(const float4*)(br + o); wr[4*m]=v.x; wr[4*m+1]=v.y; wr[4*m+2]=v.z; wr[4*m+3]=v.w;
            v = *(const float4*)(bz + o); wz[4*m]=v.x; wz[4*m+1]=v.y; wz[4*m+2]=v.z; wz[4*m+3]=v.w;
            v = *(const float4*)(bn + o); wn[4*m]=v.x; wn[4*m+1]=v.y; wn[4*m+2]=v.z; wn[4*m+3]=v.w;
        }
    }

    // all lanes carry the biases (all lanes compute the gate math)
    const float bhr = b_hh[i];
    const float bhz = b_hh[RHH + i];
    const float bhn = b_hh[2 * RHH + i];

    if (tid < HH) smem[HB0 + tid] = 0.f;       // h0 = 0 in ping buffer
    const float* xbase = xg + (size_t)b * TTT * 3 * RHH;
    float xnext = 0.f;
    if (tid < 3 * RHH) {
        smem[XG0 + tid] = xbase[tid];          // t = 0
        xnext = xbase[3 * RHH + tid];          // t = 1
    }
    float hprev = 0.f;
    float* hob = h_out + (size_t)b * TTT * HH;
    __syncthreads();

    for (int t = 0; t < TTT; t++) {
        const float* hrow = &smem[HB0 + ((t & 1) << 7)];
        float ar = 0.f, az = 0.f, an = 0.f;
        #pragma unroll
        for (int m = 0; m < 4; m++) {
            float4 hv = *(const float4*)(hrow + loff[m]);
            ar = fmaf(hv.x, wr[4*m], fmaf(hv.y, wr[4*m+1], fmaf(hv.z, wr[4*m+2], fmaf(hv.w, wr[4*m+3], ar))));
            az = fmaf(hv.x, wz[4*m], fmaf(hv.y, wz[4*m+1], fmaf(hv.z, wz[4*m+2], fmaf(hv.w, wz[4*m+3], az))));
            an = fmaf(hv.x, wn[4*m], fmaf(hv.y, wn[4*m+1], fmaf(hv.z, wn[4*m+2], fmaf(hv.w, wn[4*m+3], an))));
        }

        // publish next step's xg while dots are in flight
        if (tid < 3 * RHH) {
            smem[XG0 + (((t + 1) & 1) * 3 * RHH) + tid] = xnext;
            xnext = (t + 2 < TTT) ? xbase[(size_t)(t + 2) * 3 * RHH + tid] : 0.f;
        }

        // reduce across the 8 q-slices (lane bits 3..5); result in ALL lanes
        ar += __shfl_xor(ar, 8); ar += __shfl_xor(ar, 16); ar += __shfl_xor(ar, 32);
        az += __shfl_xor(az, 8); az += __shfl_xor(az, 16); az += __shfl_xor(az, 32);
        an += __shfl_xor(an, 8); an += __shfl_xor(an, 16); an += __shfl_xor(an, 32);

        // all q-lanes compute the gates redundantly (no divergent tail)
        {
            const float* xr_s = &smem[XG0 + ((t & 1) * 3 * RHH)];
            float xr = xr_s[i], xz = xr_s[RHH + i], xn = xr_s[2 * RHH + i];
            float sr = xr + ar + bhr;
            float sz = xz + az + bhz;
            float rg = 1.f / (1.f + __expf(-sr));
            float zg = 1.f / (1.f + __expf(-sz));
            float tv = fmaf(rg, an + bhn, xn);
            tv = fminf(fmaxf(tv, -15.f), 15.f);
            float e2 = __expf(-2.f * tv);
            float ng = (1.f - e2) / (1.f + e2);
            hprev = fmaf(zg, hprev, (1.f - zg) * ng);
            if (q == 0) {
                smem[HB0 + (((t + 1) & 1) << 7) + i] = hprev;  // LDS for next step
                hob[t * HH + i] = hprev;                       // global, fire-and-forget
            }
        }
        __syncthreads();
    }
}

// ---------------------------------------------------------------------------
// Kernel 6: out[g,:] = h_out[g,:] @ Wp + bp   (8192x128 @ 128x2)
// ---------------------------------------------------------------------------
__global__ __launch_bounds__(256) void proj_kernel(
    const float* __restrict__ h_out, const float* __restrict__ Wp,
    const float* __restrict__ bp, float* __restrict__ out)
{
    __shared__ float wps[2 * RHH];
    __shared__ float bps[2];
    const int tid = threadIdx.x;
    if (tid < 2 * RHH) wps[tid] = Wp[tid];
    if (tid < 2) bps[tid] = bp[tid];
    __syncthreads();

    const int s = tid & 7;
    const int rl = tid >> 3;
    const size_t row = (size_t)blockIdx.x * 32 + rl;
    const float* hr = h_out + row * HH + s * 16;
    float a0 = 0.f, a1 = 0.f;
    #pragma unroll
    for (int m = 0; m < 16; m += 4) {
        float4 hv = *(const float4*)(hr + m);
        int k = s * 16 + m;
        a0 = fmaf(hv.x, wps[(k+0)*2], fmaf(hv.y, wps[(k+1)*2], fmaf(hv.z, wps[(k+2)*2], fmaf(hv.w, wps[(k+3)*2], a0))));
        a1 = fmaf(hv.x, wps[(k+0)*2+1], fmaf(hv.y, wps[(k+1)*2+1], fmaf(hv.z, wps[(k+2)*2+1], fmaf(hv.w, wps[(k+3)*2+1], a1))));
    }
    a0 += __shfl_xor(a0, 1); a0 += __shfl_xor(a0, 2); a0 += __shfl_xor(a0, 4);
    a1 += __shfl_xor(a1, 1); a1 += __shfl_xor(a1, 2); a1 += __shfl_xor(a1, 4);
    if (s == 0) {
        out[row * 2 + 0] = a0 + bps[0];
        out[row * 2 + 1] = a1 + bps[1];
    }
}

extern "C" void kernel_launch(void* const* d_in, const int* in_sizes, int n_in,
                              void* d_out, int out_size, void* d_ws, size_t ws_size,
                              hipStream_t stream)
{
    const float* x      = (const float*)d_in[0];
    const int*   eidx   = (const int*)d_in[1];
    const int*   runner = (const int*)d_in[2];
    const float* W1     = (const float*)d_in[3];
    const float* b1     = (const float*)d_in[4];
    const float* W2     = (const float*)d_in[5];
    const float* b2     = (const float*)d_in[6];
    const float* W_ih   = (const float*)d_in[7];
    const float* W_hh   = (const float*)d_in[8];
    const float* b_ih   = (const float*)d_in[9];
    const float* b_hh   = (const float*)d_in[10];
    const float* Wp     = (const float*)d_in[11];
    const float* bp     = (const float*)d_in[12];
    float* out = (float*)d_out;

    float* seq    = (float*)d_ws;                    // 8192*128   [0, 4 MB)
    float* xg     = seq + (size_t)GG * HH;           // 8192*384   [4, 16.6 MB)
    float* WT     = xg + (size_t)GG * 3 * RHH;       // 128*384
    float* hsum_g = xg;   // alias: dead before xg_kernel writes xg
    float* h_out  = seq;  // alias: seq is dead once xg is built; same size

    transpose_wih<<<192, 256, 0, stream>>>(W_ih, WT);
    gcn_hsum<<<GG, 256, 0, stream>>>(x, eidx, runner, W1, b1, hsum_g);
    seq_kernel<<<GG / 16, 256, 0, stream>>>(hsum_g, W2, b2, seq);
    xg_kernel<<<GG / 8, 384, 0, stream>>>(seq, WT, b_ih, xg);
    gru_kernel<<<BBB, 1024, 0, stream>>>(xg, W_hh, b_hh, h_out);
    proj_kernel<<<GG / 32, 256, 0, stream>>>(h_out, Wp, bp, out);
}

// Round 8
// 272.979 us; speedup vs baseline: 1.0122x; 1.0122x over previous
//
#include <hip/hip_runtime.h>
#include <hip/hip_bf16.h>
#include <math.h>

#define GG 8192      // graphs = B*T
#define NODESN 23
#define KK 8
#define DIN 16
#define HH 128
#define RHH 128
#define EPG (NODESN*KK)   // 184 edges per graph
#define TTT 128
#define BBB 64

// ---------------------------------------------------------------------------
// Kernel 1: per-graph GCN up to hsum (layer-1 + neighborhood aggregation).
// ---------------------------------------------------------------------------
__global__ __launch_bounds__(256) void gcn_hsum(
    const float* __restrict__ x, const int* __restrict__ esrc,
    const int* __restrict__ runner,
    const float* __restrict__ W1, const float* __restrict__ b1,
    float* __restrict__ hsum_g)
{
    __shared__ float xs[NODESN * DIN];
    __shared__ int   srcs[EPG];
    __shared__ float t1[NODESN * HH];
    __shared__ float red[256];

    const int g   = blockIdx.x;
    const int tid = threadIdx.x;
    const int j   = tid & 127;
    const int nh  = tid >> 7;

    for (int i = tid; i < NODESN * DIN; i += 256) xs[i] = x[g * NODESN * DIN + i];
    for (int i = tid; i < EPG; i += 256)          srcs[i] = esrc[g * EPG + i] - g * NODESN;

    float w[DIN];
    #pragma unroll
    for (int k = 0; k < DIN; k++) w[k] = W1[k * HH + j];
    const float b1j = b1[j];
    __syncthreads();

    const int n0 = nh * 12;
    const int n1 = nh ? NODESN : 12;
    for (int n = n0; n < n1; n++) {
        float acc = 0.f;
        #pragma unroll
        for (int k = 0; k < DIN; k += 4) {
            float4 xv = *(const float4*)&xs[n * DIN + k];
            acc = fmaf(xv.x, w[k], fmaf(xv.y, w[k+1], fmaf(xv.z, w[k+2], fmaf(xv.w, w[k+3], acc))));
        }
        t1[n * HH + j] = acc;
    }
    __syncthreads();

    const int r = runner[g];
    float part = 0.f;
    for (int slot = nh; slot < 9; slot += 2) {
        int node = (slot < 8) ? srcs[r * KK + slot] : r;
        float acc = t1[node * HH + j];
        #pragma unroll
        for (int k = 0; k < KK; k++) acc += t1[srcs[node * KK + k] * HH + j];
        part += fmaxf(acc * (1.f / 9.f) + b1j, 0.f);
    }
    red[tid] = part;
    __syncthreads();
    if (tid < HH) hsum_g[(size_t)g * HH + tid] = red[tid] + red[tid + 128];
}

// ---------------------------------------------------------------------------
// Kernel 2: seq = relu((1/9) * hsum @ W2 + b2), 16 graphs per block.
// ---------------------------------------------------------------------------
__global__ __launch_bounds__(256) void seq_kernel(
    const float* __restrict__ hsum_g, const float* __restrict__ W2,
    const float* __restrict__ b2, float* __restrict__ seq)
{
    __shared__ float hs[16 * HH];
    const int tid = threadIdx.x;
    const int j = tid & 127, mh = tid >> 7;
    const size_t base = (size_t)blockIdx.x * 16 * HH;

    for (int v = tid; v < 16 * HH / 4; v += 256)
        ((float4*)hs)[v] = ((const float4*)(hsum_g + base))[v];
    __syncthreads();

    float acc[8];
    #pragma unroll
    for (int m = 0; m < 8; m++) acc[m] = 0.f;
    const float* hrow = hs + mh * 8 * HH;
    for (int k = 0; k < HH; k += 4) {
        float w0  = W2[(k+0)*HH + j];
        float w1  = W2[(k+1)*HH + j];
        float w2v = W2[(k+2)*HH + j];
        float w3  = W2[(k+3)*HH + j];
        #pragma unroll
        for (int m = 0; m < 8; m++) {
            float4 hv = *(const float4*)&hrow[m * HH + k];
            acc[m] = fmaf(hv.x, w0, fmaf(hv.y, w1, fmaf(hv.z, w2v, fmaf(hv.w, w3, acc[m]))));
        }
    }
    const float bj = b2[j];
    #pragma unroll
    for (int m = 0; m < 8; m++)
        seq[base + (size_t)(mh * 8 + m) * HH + j] = fmaxf(acc[m] * (1.f/9.f) + bj, 0.f);
}

// ---------------------------------------------------------------------------
// Kernel 3: transpose W_ih [384,128] -> WT [128,384]
// ---------------------------------------------------------------------------
__global__ void transpose_wih(const float* __restrict__ W, float* __restrict__ WT)
{
    int idx = blockIdx.x * 256 + threadIdx.x;
    if (idx < 3 * RHH * RHH) {
        int jj = idx / RHH, kk = idx - jj * RHH;
        WT[kk * (3 * RHH) + jj] = W[idx];
    }
}

// ---------------------------------------------------------------------------
// Kernel 4: xg = seq @ W_ih^T + b_ih   [8192,128]@[128,384]
// ---------------------------------------------------------------------------
__global__ __launch_bounds__(384) void xg_kernel(
    const float* __restrict__ seq, const float* __restrict__ WT,
    const float* __restrict__ b_ih, float* __restrict__ xg)
{
    const int tid = threadIdx.x;
    const int m0 = blockIdx.x * 8;
    const float* srow = seq + (size_t)m0 * RHH;
    float acc[8];
    const float bv = b_ih[tid];
    #pragma unroll
    for (int mi = 0; mi < 8; mi++) acc[mi] = bv;
    for (int k = 0; k < RHH; k += 4) {
        float w0 = WT[(k+0)*384 + tid];
        float w1 = WT[(k+1)*384 + tid];
        float w2 = WT[(k+2)*384 + tid];
        float w3 = WT[(k+3)*384 + tid];
        #pragma unroll
        for (int mi = 0; mi < 8; mi++) {
            float4 sv = *(const float4*)(srow + mi * RHH + k);
            acc[mi] = fmaf(sv.x, w0, fmaf(sv.y, w1, fmaf(sv.z, w2, fmaf(sv.w, w3, acc[mi]))));
        }
    }
    #pragma unroll
    for (int mi = 0; mi < 8; mi++)
        xg[(size_t)(m0 + mi) * 384 + tid] = acc[mi];
}

// ---------------------------------------------------------------------------
// Kernel 5: GRU with a 100% VMEM-FREE steady-state loop + fused projection.
// 1024 threads per batch element; thread (i,q): i = hidden unit, q = k-eighth
// (48 W_hh floats/thread, asm-pinned). xg staged into LDS in 64-step chunks;
// h rows go to an LDS buffer (no global h traffic); out = h @ Wp + bp is
// computed per chunk from LDS. Rationale: R4-R7 all spilled the weights
// (VGPR 44-88 vs 48-96 needed) -- the scheduler treats loops containing
// global loads/stores as latency-bound and sinks the weight loads. With zero
// in-loop vmem + 133 KB LDS (1 block/CU -> 128-reg budget) + post-load pins,
// there is no remaining reason to spill.
// ---------------------------------------------------------------------------
#define CHUNK 64
#define XGBUF_FLOATS (CHUNK * 3 * RHH)   // 24576 -> 98304 B
#define HOUT_FLOATS  (CHUNK * HH)        // 8192  -> 32768 B

__global__ __launch_bounds__(1024)
__attribute__((amdgpu_waves_per_eu(4, 4)))
void gru_kernel(
    const float* __restrict__ xg, const float* __restrict__ W_hh,
    const float* __restrict__ b_hh, const float* __restrict__ Wp,
    const float* __restrict__ bp, float* __restrict__ out)
{
    __shared__ float xgbuf[XGBUF_FLOATS];   // 98304 B
    __shared__ float houtb[HOUT_FLOATS];    // 32768 B
    __shared__ float hpp[2 * HH];           // 1024 B
    __shared__ float wps[2 * RHH + 2];      // 1032 B   (Wp + bp)
    // total ~133 KB: > 80 KB -> exactly 1 block/CU

    const int b    = blockIdx.x;
    const int tid  = threadIdx.x;
    const int lane = tid & 63;
    const int q    = lane >> 3;                          // k-eighth 0..7
    const int i    = ((tid >> 6) << 3) | (lane & 7);     // hidden unit 0..127

    // ---- preload W_hh slices (rows i, 128+i, 256+i; cols [16q,16q+16)),
    // phase-rotated (p = (m+q)&3) to spread LDS bank groups across q.
    float wr[16], wz[16], wn[16];
    int loff[4];
    {
        const float* br = W_hh + (size_t)i * RHH;
        const float* bz = br + (size_t)RHH * RHH;
        const float* bn = bz + (size_t)RHH * RHH;
        #pragma unroll
        for (int m = 0; m < 4; m++) {
            int p = (m + q) & 3;
            int o = q * 16 + 4 * p;
            loff[m] = o;
            float4 v;
            v = *(const float4*)(br + o); wr[4*m]=v.x; wr[4*m+1]=v.y; wr[4*m+2]=v.z; wr[4*m+3]=v.w;
            v = *(const float4*)(bz + o); wz[4*m]=v.x; wz[4*m+1]=v.y; wz[4*m+2]=v.z; wz[4*m+3]=v.w;
            v = *(const float4*)(bn + o); wn[4*m]=v.x; wn[4*m+1]=v.y; wn[4*m+2]=v.z; wn[4*m+3]=v.w;
        }
    }
    // pin: post-asm values are opaque (cannot be rematerialized from memory)
    #pragma unroll
    for (int m = 0; m < 16; m++) {
        asm("" : "+v"(wr[m]));
        asm("" : "+v"(wz[m]));
        asm("" : "+v"(wn[m]));
    }

    const float bhr = b_hh[i];
    const float bhz = b_hh[RHH + i];
    const float bhn = b_hh[2 * RHH + i];

    if (tid < 2 * RHH) wps[tid] = Wp[tid];
    if (tid < 2)       wps[2 * RHH + tid] = bp[tid];
    if (tid < HH)      hpp[tid] = 0.f;        // h0 = 0 (ping slot 0)
    float hprev = 0.f;

    const float* xbase = xg + (size_t)b * TTT * 3 * RHH;
    float* outb = out + (size_t)b * TTT * 2;

    for (int c = 0; c < TTT / CHUNK; c++) {
        // ---- chunk prologue: refill xg buffer; project previous chunk ----
        {
            const float4* src = (const float4*)(xbase + (size_t)c * XGBUF_FLOATS);
            #pragma unroll
            for (int v = 0; v < XGBUF_FLOATS / 4 / 1024; v++)
                ((float4*)xgbuf)[tid + v * 1024] = src[tid + v * 1024];
        }
        if (c > 0) {
            const int s  = tid & 7;               // k-slice (shfl 1,2,4)
            const int cc = (tid >> 3) & 1;        // output column
            const int tl = tid >> 4;              // local timestep 0..63
            const float* hr = &houtb[tl * HH + s * 16];
            float acc = 0.f;
            #pragma unroll
            for (int m = 0; m < 16; m += 4) {
                float4 hv = *(const float4*)(hr + m);
                int k = s * 16 + m;
                acc = fmaf(hv.x, wps[(k+0)*2 + cc],
                      fmaf(hv.y, wps[(k+1)*2 + cc],
                      fmaf(hv.z, wps[(k+2)*2 + cc],
                      fmaf(hv.w, wps[(k+3)*2 + cc], acc))));
            }
            acc += __shfl_xor(acc, 1); acc += __shfl_xor(acc, 2); acc += __shfl_xor(acc, 4);
            if (s == 0)
                outb[((c - 1) * CHUNK + tl) * 2 + cc] = acc + wps[2 * RHH + cc];
        }
        __syncthreads();

        // ---- 64 steps, zero vmem ----
        for (int tl = 0; tl < CHUNK; tl++) {
            const float* hrow = &hpp[(tl & 1) * HH];
            float ar = 0.f, az = 0.f, an = 0.f;
            #pragma unroll
            for (int m = 0; m < 4; m++) {
                float4 hv = *(const float4*)(hrow + loff[m]);
                ar = fmaf(hv.x, wr[4*m], fmaf(hv.y, wr[4*m+1], fmaf(hv.z, wr[4*m+2], fmaf(hv.w, wr[4*m+3], ar))));
                az = fmaf(hv.x, wz[4*m], fmaf(hv.y, wz[4*m+1], fmaf(hv.z, wz[4*m+2], fmaf(hv.w, wz[4*m+3], az))));
                an = fmaf(hv.x, wn[4*m], fmaf(hv.y, wn[4*m+1], fmaf(hv.z, wn[4*m+2], fmaf(hv.w, wn[4*m+3], an))));
            }

            // reduce across the 8 q-slices (lane bits 3..5); result in ALL lanes
            ar += __shfl_xor(ar, 8); ar += __shfl_xor(ar, 16); ar += __shfl_xor(ar, 32);
            az += __shfl_xor(az, 8); az += __shfl_xor(az, 16); az += __shfl_xor(az, 32);
            an += __shfl_xor(an, 8); an += __shfl_xor(an, 16); an += __shfl_xor(an, 32);

            // all lanes compute the gates (uniform, no divergent tail)
            {
                float xr = xgbuf[tl * 384 + i];
                float xz = xgbuf[tl * 384 + RHH + i];
                float xn = xgbuf[tl * 384 + 2 * RHH + i];
                float sr = xr + ar + bhr;
                float sz = xz + az + bhz;
                float rg = 1.f / (1.f + __expf(-sr));
                float zg = 1.f / (1.f + __expf(-sz));
                float tv = fmaf(rg, an + bhn, xn);
                tv = fminf(fmaxf(tv, -15.f), 15.f);
                float e2 = __expf(-2.f * tv);
                float ng = (1.f - e2) / (1.f + e2);
                hprev = fmaf(zg, hprev, (1.f - zg) * ng);
                if (q == 0) {
                    hpp[((tl + 1) & 1) * HH + i] = hprev;   // for next step
                    houtb[tl * HH + i] = hprev;             // for projection
                }
            }
            __syncthreads();
        }
    }

    // ---- project the last chunk ----
    {
        const int s  = tid & 7;
        const int cc = (tid >> 3) & 1;
        const int tl = tid >> 4;
        const float* hr = &houtb[tl * HH + s * 16];
        float acc = 0.f;
        #pragma unroll
        for (int m = 0; m < 16; m += 4) {
            float4 hv = *(const float4*)(hr + m);
            int k = s * 16 + m;
            acc = fmaf(hv.x, wps[(k+0)*2 + cc],
                  fmaf(hv.y, wps[(k+1)*2 + cc],
                  fmaf(hv.z, wps[(k+2)*2 + cc],
                  fmaf(hv.w, wps[(k+3)*2 + cc], acc))));
        }
        acc += __shfl_xor(acc, 1); acc += __shfl_xor(acc, 2); acc += __shfl_xor(acc, 4);
        if (s == 0)
            outb[((TTT / CHUNK - 1) * CHUNK + tl) * 2 + cc] = acc + wps[2 * RHH + cc];
    }
}

extern "C" void kernel_launch(void* const* d_in, const int* in_sizes, int n_in,
                              void* d_out, int out_size, void* d_ws, size_t ws_size,
                              hipStream_t stream)
{
    const float* x      = (const float*)d_in[0];
    const int*   eidx   = (const int*)d_in[1];
    const int*   runner = (const int*)d_in[2];
    const float* W1     = (const float*)d_in[3];
    const float* b1     = (const float*)d_in[4];
    const float* W2     = (const float*)d_in[5];
    const float* b2     = (const float*)d_in[6];
    const float* W_ih   = (const float*)d_in[7];
    const float* W_hh   = (const float*)d_in[8];
    const float* b_ih   = (const float*)d_in[9];
    const float* b_hh   = (const float*)d_in[10];
    const float* Wp     = (const float*)d_in[11];
    const float* bp     = (const float*)d_in[12];
    float* out = (float*)d_out;

    float* seq    = (float*)d_ws;                    // 8192*128   [0, 4 MB)
    float* xg     = seq + (size_t)GG * HH;           // 8192*384   [4, 16.6 MB)
    float* WT     = xg + (size_t)GG * 3 * RHH;       // 128*384
    float* hsum_g = xg;   // alias: dead before xg_kernel writes xg

    transpose_wih<<<192, 256, 0, stream>>>(W_ih, WT);
    gcn_hsum<<<GG, 256, 0, stream>>>(x, eidx, runner, W1, b1, hsum_g);
    seq_kernel<<<GG / 16, 256, 0, stream>>>(hsum_g, W2, b2, seq);
    xg_kernel<<<GG / 8, 384, 0, stream>>>(seq, WT, b_ih, xg);
    gru_kernel<<<BBB, 1024, 0, stream>>>(xg, W_hh, b_hh, Wp, bp, out);
}

// Round 9
// 243.321 us; speedup vs baseline: 1.1356x; 1.1219x over previous
//
#include <hip/hip_runtime.h>
#include <hip/hip_bf16.h>
#include <math.h>

#define GG 8192      // graphs = B*T
#define NODESN 23
#define KK 8
#define DIN 16
#define HH 128
#define RHH 128
#define EPG (NODESN*KK)   // 184 edges per graph
#define TTT 128
#define BBB 64

// ---------------------------------------------------------------------------
// DPP cross-lane add (VALU pipe -- NOT the DS pipe, unlike __shfl_xor).
// ---------------------------------------------------------------------------
template<int CTRL>
static __device__ __forceinline__ float dpp_add(float v) {
    int x = __builtin_amdgcn_update_dpp(0, __float_as_int(v), CTRL, 0xF, 0xF, true);
    return v + __int_as_float(x);
}
#define DPP_XOR1 0xB1   // quad_perm [1,0,3,2]
#define DPP_XOR2 0x4E   // quad_perm [2,3,0,1]
#define DPP_SHL4 0x104  // row_shl:4 (lane l <- lane l+4)

// ---------------------------------------------------------------------------
// Kernel 1: per-graph GCN up to hsum (layer-1 + neighborhood aggregation).
// ---------------------------------------------------------------------------
__global__ __launch_bounds__(256) void gcn_hsum(
    const float* __restrict__ x, const int* __restrict__ esrc,
    const int* __restrict__ runner,
    const float* __restrict__ W1, const float* __restrict__ b1,
    float* __restrict__ hsum_g)
{
    __shared__ float xs[NODESN * DIN];
    __shared__ int   srcs[EPG];
    __shared__ float t1[NODESN * HH];
    __shared__ float red[256];

    const int g   = blockIdx.x;
    const int tid = threadIdx.x;
    const int j   = tid & 127;
    const int nh  = tid >> 7;

    for (int i = tid; i < NODESN * DIN; i += 256) xs[i] = x[g * NODESN * DIN + i];
    for (int i = tid; i < EPG; i += 256)          srcs[i] = esrc[g * EPG + i] - g * NODESN;

    float w[DIN];
    #pragma unroll
    for (int k = 0; k < DIN; k++) w[k] = W1[k * HH + j];
    const float b1j = b1[j];
    __syncthreads();

    const int n0 = nh * 12;
    const int n1 = nh ? NODESN : 12;
    for (int n = n0; n < n1; n++) {
        float acc = 0.f;
        #pragma unroll
        for (int k = 0; k < DIN; k += 4) {
            float4 xv = *(const float4*)&xs[n * DIN + k];
            acc = fmaf(xv.x, w[k], fmaf(xv.y, w[k+1], fmaf(xv.z, w[k+2], fmaf(xv.w, w[k+3], acc))));
        }
        t1[n * HH + j] = acc;
    }
    __syncthreads();

    const int r = runner[g];
    float part = 0.f;
    for (int slot = nh; slot < 9; slot += 2) {
        int node = (slot < 8) ? srcs[r * KK + slot] : r;
        float acc = t1[node * HH + j];
        #pragma unroll
        for (int k = 0; k < KK; k++) acc += t1[srcs[node * KK + k] * HH + j];
        part += fmaxf(acc * (1.f / 9.f) + b1j, 0.f);
    }
    red[tid] = part;
    __syncthreads();
    if (tid < HH) hsum_g[(size_t)g * HH + tid] = red[tid] + red[tid + 128];
}

// ---------------------------------------------------------------------------
// Kernel 2: seq = relu((1/9) * hsum @ W2 + b2), 16 graphs per block.
// ---------------------------------------------------------------------------
__global__ __launch_bounds__(256) void seq_kernel(
    const float* __restrict__ hsum_g, const float* __restrict__ W2,
    const float* __restrict__ b2, float* __restrict__ seq)
{
    __shared__ float hs[16 * HH];
    const int tid = threadIdx.x;
    const int j = tid & 127, mh = tid >> 7;
    const size_t base = (size_t)blockIdx.x * 16 * HH;

    for (int v = tid; v < 16 * HH / 4; v += 256)
        ((float4*)hs)[v] = ((const float4*)(hsum_g + base))[v];
    __syncthreads();

    float acc[8];
    #pragma unroll
    for (int m = 0; m < 8; m++) acc[m] = 0.f;
    const float* hrow = hs + mh * 8 * HH;
    for (int k = 0; k < HH; k += 4) {
        float w0  = W2[(k+0)*HH + j];
        float w1  = W2[(k+1)*HH + j];
        float w2v = W2[(k+2)*HH + j];
        float w3  = W2[(k+3)*HH + j];
        #pragma unroll
        for (int m = 0; m < 8; m++) {
            float4 hv = *(const float4*)&hrow[m * HH + k];
            acc[m] = fmaf(hv.x, w0, fmaf(hv.y, w1, fmaf(hv.z, w2v, fmaf(hv.w, w3, acc[m]))));
        }
    }
    const float bj = b2[j];
    #pragma unroll
    for (int m = 0; m < 8; m++)
        seq[base + (size_t)(mh * 8 + m) * HH + j] = fmaxf(acc[m] * (1.f/9.f) + bj, 0.f);
}

// ---------------------------------------------------------------------------
// Kernel 3: transpose W_ih [384,128] -> WT [128,384]
// ---------------------------------------------------------------------------
__global__ void transpose_wih(const float* __restrict__ W, float* __restrict__ WT)
{
    int idx = blockIdx.x * 256 + threadIdx.x;
    if (idx < 3 * RHH * RHH) {
        int jj = idx / RHH, kk = idx - jj * RHH;
        WT[kk * (3 * RHH) + jj] = W[idx];
    }
}

// ---------------------------------------------------------------------------
// Kernel 4: xg = seq @ W_ih^T + b_ih   [8192,128]@[128,384]
// ---------------------------------------------------------------------------
__global__ __launch_bounds__(384) void xg_kernel(
    const float* __restrict__ seq, const float* __restrict__ WT,
    const float* __restrict__ b_ih, float* __restrict__ xg)
{
    const int tid = threadIdx.x;
    const int m0 = blockIdx.x * 8;
    const float* srow = seq + (size_t)m0 * RHH;
    float acc[8];
    const float bv = b_ih[tid];
    #pragma unroll
    for (int mi = 0; mi < 8; mi++) acc[mi] = bv;
    for (int k = 0; k < RHH; k += 4) {
        float w0 = WT[(k+0)*384 + tid];
        float w1 = WT[(k+1)*384 + tid];
        float w2 = WT[(k+2)*384 + tid];
        float w3 = WT[(k+3)*384 + tid];
        #pragma unroll
        for (int mi = 0; mi < 8; mi++) {
            float4 sv = *(const float4*)(srow + mi * RHH + k);
            acc[mi] = fmaf(sv.x, w0, fmaf(sv.y, w1, fmaf(sv.z, w2, fmaf(sv.w, w3, acc[mi]))));
        }
    }
    #pragma unroll
    for (int mi = 0; mi < 8; mi++)
        xg[(size_t)(m0 + mi) * 384 + tid] = acc[mi];
}

// ---------------------------------------------------------------------------
// Kernel 5: GRU, DS-pipe-minimized. 512 threads (8 waves) per batch element.
// Thread (i,q): i = tid>>2 (hidden unit), q = tid&3 (k-quarter, lane bits 0-1)
// -> 96 W_hh floats/thread (AGPR-backed if trimmed: cheap VALU reloads, no
// memory). Per step per CU DS budget: 64 h-reads (b128, phase-rotated,
// conflict-free) + 8 xg reads (b128, repacked [t][i][rzn_]) + 8 h-writes
// = ~80 DS instr vs R8's ~256 (144 of which were __shfl = ds_bpermute).
// q-reduction is pure-VALU DPP quad_perm (xor1+xor2 -> full sum in ALL lanes).
// h ping-pong lives inside houtb (read row tl, write row tl+1); projection
// out = h @ Wp + bp fused per 32-step chunk. 84 KB LDS -> 1 block/CU.
// ---------------------------------------------------------------------------
#define CHUNK 32
#define XGB_FLOATS (CHUNK * HH * 4)      // 16384 floats = 64 KB

__global__ __launch_bounds__(512)
__attribute__((amdgpu_waves_per_eu(2, 2)))
void gru_kernel(
    const float* __restrict__ xg, const float* __restrict__ W_hh,
    const float* __restrict__ b_hh, const float* __restrict__ Wp,
    const float* __restrict__ bp, float* __restrict__ out)
{
    __shared__ float xgbuf[XGB_FLOATS];          // [tl][i][{xr,xz,xn,pad}]
    __shared__ float houtb[(CHUNK + 2) * HH];    // rows 1..32 = h(t); row 32 also carry
    __shared__ float wps[2 * RHH + 2];           // Wp + bp
    // total 83.9 KB -> exactly 1 block/CU (2 would need >160 KiB)

    const int b   = blockIdx.x;
    const int tid = threadIdx.x;
    const int q   = tid & 3;       // k-quarter, lane bits 0-1 (quad_perm domain)
    const int i   = tid >> 2;      // hidden unit 0..127

    // ---- preload W_hh slices (rows i, 128+i, 256+i; cols [32q,32q+32)),
    // phase-rotated (p = (m+2q)&7): proven conflict-free in R6.
    float4 wrv[8], wzv[8], wnv[8];
    int lof[8];
    {
        const float* br = W_hh + (size_t)i * RHH + q * 32;
        const float* bz = br + (size_t)RHH * RHH;
        const float* bn = bz + (size_t)RHH * RHH;
        #pragma unroll
        for (int m = 0; m < 8; m++) {
            int p = (m + 2 * q) & 7;
            lof[m] = q * 32 + 4 * p;
            wrv[m] = *(const float4*)(br + 4 * p);
            wzv[m] = *(const float4*)(bz + 4 * p);
            wnv[m] = *(const float4*)(bn + 4 * p);
        }
    }
    const float bhr = b_hh[i];
    const float bhz = b_hh[RHH + i];
    const float bhn = b_hh[2 * RHH + i];

    if (tid < 2 * RHH) wps[tid] = Wp[tid];
    if (tid < 2)       wps[2 * RHH + tid] = bp[tid];
    if (tid < HH)      houtb[CHUNK * HH + tid] = 0.f;   // carry row = h(-1) = 0
    float hprev = 0.f;

    const float* xbase = xg + (size_t)b * TTT * 3 * RHH;
    float* outb = out + (size_t)b * TTT * 2;

    for (int c = 0; c < TTT / CHUNK; c++) {
        // ---- refill xgbuf for chunk c, repacking to [tl][i][{r,z,n,pad}]
        #pragma unroll
        for (int k2 = 0; k2 < 8; k2++) {
            int slot = tid + (k2 << 9);          // 0..4095
            int tl = slot >> 7, ii = slot & 127;
            const float* gsrc = xbase + (size_t)(c * CHUNK + tl) * 384 + ii;
            float4 v;
            v.x = gsrc[0]; v.y = gsrc[128]; v.z = gsrc[256]; v.w = 0.f;
            *(float4*)&xgbuf[slot << 2] = v;
        }
        // ---- project previous chunk: out = houtb[1..32] @ Wp + bp
        if (c > 0) {
            const int s  = tid & 7;              // 16-float k-slice
            const int cc = (tid >> 3) & 1;
            const int tl = tid >> 4;             // 0..31
            const float* hr = &houtb[(tl + 1) * HH + s * 16];
            float acc = 0.f;
            #pragma unroll
            for (int m = 0; m < 16; m += 4) {
                float4 hv = *(const float4*)(hr + m);
                int k = s * 16 + m;
                acc = fmaf(hv.x, wps[(k+0)*2 + cc],
                      fmaf(hv.y, wps[(k+1)*2 + cc],
                      fmaf(hv.z, wps[(k+2)*2 + cc],
                      fmaf(hv.w, wps[(k+3)*2 + cc], acc))));
            }
            acc = dpp_add<DPP_XOR1>(acc);
            acc = dpp_add<DPP_XOR2>(acc);
            acc = dpp_add<DPP_SHL4>(acc);        // valid in lanes s<4
            if (s == 0)
                outb[((c - 1) * CHUNK + tl) * 2 + cc] = acc + wps[2 * RHH + cc];
        }
        __syncthreads();

        // ---- 32 steps; per step: 8 ds_read_b128 (h) + 1 (xg) + 1 write
        for (int tl = 0; tl < CHUNK; tl++) {
            const float* hrow = &houtb[(tl == 0 ? CHUNK : tl) * HH];
            float4 xgv = *(const float4*)&xgbuf[(tl * HH + i) << 2]; // early: overlaps dots
            float ar = 0.f, az = 0.f, an = 0.f;
            #pragma unroll
            for (int m = 0; m < 8; m++) {
                float4 hv = *(const float4*)(hrow + lof[m]);
                ar = fmaf(hv.x, wrv[m].x, fmaf(hv.y, wrv[m].y, fmaf(hv.z, wrv[m].z, fmaf(hv.w, wrv[m].w, ar))));
                az = fmaf(hv.x, wzv[m].x, fmaf(hv.y, wzv[m].y, fmaf(hv.z, wzv[m].z, fmaf(hv.w, wzv[m].w, az))));
                an = fmaf(hv.x, wnv[m].x, fmaf(hv.y, wnv[m].y, fmaf(hv.z, wnv[m].z, fmaf(hv.w, wnv[m].w, an))));
            }
            // q-reduction: pure VALU (DPP quad_perm butterfly), 0 DS ops
            ar = dpp_add<DPP_XOR1>(ar); ar = dpp_add<DPP_XOR2>(ar);
            az = dpp_add<DPP_XOR1>(az); az = dpp_add<DPP_XOR2>(az);
            an = dpp_add<DPP_XOR1>(an); an = dpp_add<DPP_XOR2>(an);

            // all lanes compute gates (uniform); q==0 publishes
            float sr = xgv.x + ar + bhr;
            float sz = xgv.y + az + bhz;
            float rg = 1.f / (1.f + __expf(-sr));
            float zg = 1.f / (1.f + __expf(-sz));
            float tv = fmaf(rg, an + bhn, xgv.z);
            tv = fminf(fmaxf(tv, -15.f), 15.f);
            float e2 = __expf(-2.f * tv);
            float ng = (1.f - e2) / (1.f + e2);
            hprev = fmaf(zg, hprev, (1.f - zg) * ng);
            if (q == 0) houtb[(tl + 1) * HH + i] = hprev;
            __syncthreads();
        }
    }

    // ---- project the last chunk
    {
        const int s  = tid & 7;
        const int cc = (tid >> 3) & 1;
        const int tl = tid >> 4;
        const float* hr = &houtb[(tl + 1) * HH + s * 16];
        float acc = 0.f;
        #pragma unroll
        for (int m = 0; m < 16; m += 4) {
            float4 hv = *(const float4*)(hr + m);
            int k = s * 16 + m;
            acc = fmaf(hv.x, wps[(k+0)*2 + cc],
                  fmaf(hv.y, wps[(k+1)*2 + cc],
                  fmaf(hv.z, wps[(k+2)*2 + cc],
                  fmaf(hv.w, wps[(k+3)*2 + cc], acc))));
        }
        acc = dpp_add<DPP_XOR1>(acc);
        acc = dpp_add<DPP_XOR2>(acc);
        acc = dpp_add<DPP_SHL4>(acc);
        if (s == 0)
            outb[((TTT / CHUNK - 1) * CHUNK + tl) * 2 + cc] = acc + wps[2 * RHH + cc];
    }
}

extern "C" void kernel_launch(void* const* d_in, const int* in_sizes, int n_in,
                              void* d_out, int out_size, void* d_ws, size_t ws_size,
                              hipStream_t stream)
{
    const float* x      = (const float*)d_in[0];
    const int*   eidx   = (const int*)d_in[1];
    const int*   runner = (const int*)d_in[2];
    const float* W1     = (const float*)d_in[3];
    const float* b1     = (const float*)d_in[4];
    const float* W2     = (const float*)d_in[5];
    const float* b2     = (const float*)d_in[6];
    const float* W_ih   = (const float*)d_in[7];
    const float* W_hh   = (const float*)d_in[8];
    const float* b_ih   = (const float*)d_in[9];
    const float* b_hh   = (const float*)d_in[10];
    const float* Wp     = (const float*)d_in[11];
    const float* bp     = (const float*)d_in[12];
    float* out = (float*)d_out;

    float* seq    = (float*)d_ws;                    // 8192*128   [0, 4 MB)
    float* xg     = seq + (size_t)GG * HH;           // 8192*384   [4, 16.6 MB)
    float* WT     = xg + (size_t)GG * 3 * RHH;       // 128*384
    float* hsum_g = xg;   // alias: dead before xg_kernel writes xg

    transpose_wih<<<192, 256, 0, stream>>>(W_ih, WT);
    gcn_hsum<<<GG, 256, 0, stream>>>(x, eidx, runner, W1, b1, hsum_g);
    seq_kernel<<<GG / 16, 256, 0, stream>>>(hsum_g, W2, b2, seq);
    xg_kernel<<<GG / 8, 384, 0, stream>>>(seq, WT, b_ih, xg);
    gru_kernel<<<BBB, 512, 0, stream>>>(xg, W_hh, b_hh, Wp, bp, out);
}